// Round 13
// baseline (2787.519 us; speedup 1.0000x reference)
//
#include <hip/hip_runtime.h>
#include <math.h>

// Problem constants (from reference)
#define NB 2
#define NN 2048
#define NJ 24
#define NIB 9
#define NCD 16
#define NHID 128
#define NP (NB * NN)        // 4096
#define NPI (NP * NIB)      // 36864
#define NBSTRIDE (NN * NIB) // 18432 per batch
#define SBLEND 20.0f
#define CVG_EPS 1e-5f
#define MAX_STEPS 50

#define NTHR 256            // 4 waves/block
#define PPB 32              // problems per block (4 waves x 8)
#define NBLK (NPI / PPB)    // 1152
#define HSTR 129            // (r*129+k)%32 == (r+k)%32 -> row-distinct banks

static __device__ __forceinline__ float softplusf(float x) {
    return fmaxf(x, 0.0f) + log1pf(expf(-fabsf(x)));
}
static __device__ __forceinline__ float sigmoidf(float x) {
    return 1.0f / (1.0f + expf(-x));
}
// init-bone index: {0,1,2,4,5,16,17,18,19}
static __device__ __forceinline__ int bone_of(int ib) {
    return (ib < 3) ? ib : ((ib < 5) ? ib + 1 : ib + 11);
}

template <int IMM>
static __device__ __forceinline__ float swzf(float v) {
    return __int_as_float(__builtin_amdgcn_ds_swizzle(__float_as_int(v), IMM));
}

// acc[0..15] += h * W16 (one 64B-aligned weight slice, 4x dwordx4)
static __device__ __forceinline__ void fma16q(float h, const float* __restrict__ wk,
                                              float* acc) {
    const float4 a = *(const float4*)(wk + 0);
    const float4 b = *(const float4*)(wk + 4);
    const float4 c = *(const float4*)(wk + 8);
    const float4 d = *(const float4*)(wk + 12);
    acc[0] = fmaf(h, a.x, acc[0]);   acc[1] = fmaf(h, a.y, acc[1]);
    acc[2] = fmaf(h, a.z, acc[2]);   acc[3] = fmaf(h, a.w, acc[3]);
    acc[4] = fmaf(h, b.x, acc[4]);   acc[5] = fmaf(h, b.y, acc[5]);
    acc[6] = fmaf(h, b.z, acc[6]);   acc[7] = fmaf(h, b.w, acc[7]);
    acc[8] = fmaf(h, c.x, acc[8]);   acc[9] = fmaf(h, c.y, acc[9]);
    acc[10] = fmaf(h, c.z, acc[10]); acc[11] = fmaf(h, c.w, acc[11]);
    acc[12] = fmaf(h, d.x, acc[12]); acc[13] = fmaf(h, d.y, acc[13]);
    acc[14] = fmaf(h, d.z, acc[14]); acc[15] = fmaf(h, d.w, acc[15]);
}
static __device__ __forceinline__ void load16(const float* __restrict__ p, float* acc) {
    const float4 a = *(const float4*)(p + 0);
    const float4 b = *(const float4*)(p + 4);
    const float4 c = *(const float4*)(p + 8);
    const float4 d = *(const float4*)(p + 12);
    acc[0] = a.x; acc[1] = a.y; acc[2] = a.z; acc[3] = a.w;
    acc[4] = b.x; acc[5] = b.y; acc[6] = b.z; acc[7] = b.w;
    acc[8] = c.x; acc[9] = c.y; acc[10] = c.z; acc[11] = c.w;
    acc[12] = d.x; acc[13] = d.y; acc[14] = d.z; acc[15] = d.w;
}

// hidden value layer (K=128): reads Hrow[0..127], writes softplus to own slice.
// Wave-internal LDS dependency only; compiler orders aliasing DS ops.
static __device__ __forceinline__ void hid_val(const float* __restrict__ W,
                                               const float* __restrict__ bias,
                                               float* Hrow, int jb) {
    float acc[16];
    load16(bias + jb, acc);
#pragma unroll 4
    for (int k = 0; k < NHID; k++) fma16q(Hrow[k], W + k * NHID + jb, acc);
#pragma unroll
    for (int jj = 0; jj < 16; jj++) Hrow[jb + jj] = softplusf(acc[jj]);
}

// hidden jacfwd layer: value rows softplus; tangent rows sigmoid(z_val)*z.
// Hval = value-channel row of this problem-group (r & 4).
static __device__ __forceinline__ void hid_jac(const float* __restrict__ W,
                                               const float* __restrict__ bias,
                                               float* Hrow, float* Hval, int jb,
                                               bool isval) {
    float acc[16];
    if (isval) load16(bias + jb, acc);
    else {
#pragma unroll
        for (int jj = 0; jj < 16; jj++) acc[jj] = 0.0f;
    }
#pragma unroll 4
    for (int k = 0; k < NHID; k++) fma16q(Hrow[k], W + k * NHID + jb, acc);
    // publish raw z (value rows only; consumed by tangent rows)
    if (isval) {
#pragma unroll
        for (int jj = 0; jj < 16; jj++) Hrow[jb + jj] = acc[jj];
    }
    // per-jj: read value-row z (before overwrite at same jj), transform, write
#pragma unroll
    for (int jj = 0; jj < 16; jj++) {
        float zv = Hval[jb + jj];
        Hrow[jb + jj] = isval ? softplusf(acc[jj]) : sigmoidf(zv) * acc[jj];
    }
}

// final LBS layer: 3 logits per lane (24 = 8cg x 3), writes to Lrow.
static __device__ __forceinline__ void logit_lay(const float* __restrict__ W,
                                                 const float* __restrict__ bias,
                                                 const float* Hrow, float* Lrow, int cg,
                                                 bool addbias) {
    const int jb3 = cg * 3;
    float a0 = addbias ? bias[jb3 + 0] : 0.0f;
    float a1 = addbias ? bias[jb3 + 1] : 0.0f;
    float a2 = addbias ? bias[jb3 + 2] : 0.0f;
#pragma unroll 4
    for (int k = 0; k < NHID; k++) {
        float h = Hrow[k];
        const float* w = W + k * NJ + jb3;
        a0 = fmaf(h, w[0], a0); a1 = fmaf(h, w[1], a1); a2 = fmaf(h, w[2], a2);
    }
    Lrow[jb3 + 0] = a0; Lrow[jb3 + 1] = a1; Lrow[jb3 + 2] = a2;
}

// One Broyden update (replicated across the 8 lanes of a row; in-place exp
// caching in Lrow is a benign same-value write).
static __device__ __forceinline__ void broyden_step(
    float* sLgRow, const float* sTm, float tx, float ty, float tz,
    float dx0, float dx1, float dx2,
    float& x0_, float& x1_, float& x2_, float& g0, float& g1, float& g2,
    float& Ji0, float& Ji1, float& Ji2, float& Ji3, float& Ji4, float& Ji5,
    float& Ji6, float& Ji7, float& Ji8,
    float& u0, float& u1, float& u2,
    float& bx0, float& bx1, float& bx2, float& berr) {
    float mx = -1e30f;
#pragma unroll
    for (int j = 0; j < NJ; j++) mx = fmaxf(mx, SBLEND * sLgRow[j]);
    float S = 0.0f;
#pragma unroll
    for (int j = 0; j < NJ; j++) {
        float e = expf(SBLEND * sLgRow[j] - mx);
        sLgRow[j] = e;
        S += e;
    }
    const float invS = 1.0f / S;
    float f0 = 0, f1 = 0, f2 = 0;
#pragma unroll
    for (int j = 0; j < NJ; j++) {
        float sj = sLgRow[j] * invS;
        const float* M = &sTm[j * 12];
        f0 += sj * (M[0] * x0_ + M[1] * x1_ + M[2] * x2_ + M[3]);
        f1 += sj * (M[4] * x0_ + M[5] * x1_ + M[6] * x2_ + M[7]);
        f2 += sj * (M[8] * x0_ + M[9] * x1_ + M[10] * x2_ + M[11]);
    }
    float gn0 = f0 - tx, gn1 = f1 - ty, gn2 = f2 - tz;
    float dg0 = gn0 - g0, dg1 = gn1 - g1, dg2 = gn2 - g2;
    float Jd0 = Ji0 * dg0 + Ji1 * dg1 + Ji2 * dg2;
    float Jd1 = Ji3 * dg0 + Ji4 * dg1 + Ji5 * dg2;
    float Jd2 = Ji6 * dg0 + Ji7 * dg1 + Ji8 * dg2;
    float v0 = dx0 * Ji0 + dx1 * Ji3 + dx2 * Ji6;
    float v1 = dx0 * Ji1 + dx1 * Ji4 + dx2 * Ji7;
    float v2 = dx0 * Ji2 + dx1 * Ji5 + dx2 * Ji8;
    float a0 = dx0 - Jd0, a1 = dx1 - Jd1, a2 = dx2 - Jd2;
    float bden = v0 * dg0 + v1 * dg1 + v2 * dg2 + 1e-6f;
    float s0 = a0 / bden, s1 = a1 / bden, s2 = a2 / bden;
    Ji0 += s0 * v0; Ji1 += s0 * v1; Ji2 += s0 * v2;
    Ji3 += s1 * v0; Ji4 += s1 * v1; Ji5 += s1 * v2;
    Ji6 += s2 * v0; Ji7 += s2 * v1; Ji8 += s2 * v2;
    u0 = -(Ji0 * gn0 + Ji1 * gn1 + Ji2 * gn2);
    u1 = -(Ji3 * gn0 + Ji4 * gn1 + Ji5 * gn2);
    u2 = -(Ji6 * gn0 + Ji7 * gn1 + Ji8 * gn2);
    float err = sqrtf(gn0 * gn0 + gn1 * gn1 + gn2 * gn2);
    if (err < berr) { berr = err; bx0 = x0_; bx1 = x1_; bx2 = x2_; }
    g0 = gn0; g1 = gn1; g2 = gn2;
}

// ---------------------------------------------------------------------------
// Fully fused wave-autonomous kernel. 4 waves/block, each wave owns 8 problems
// end-to-end. Zero __syncthreads in all loops (one barrier after staging).
// ---------------------------------------------------------------------------
__global__ __launch_bounds__(NTHR) void kernel_fused(
    const float* __restrict__ xd, const float* __restrict__ cond, const float* __restrict__ tfs,
    const float* __restrict__ lw0, const float* __restrict__ lb0,
    const float* __restrict__ lw1, const float* __restrict__ lb1,
    const float* __restrict__ lw2, const float* __restrict__ lb2,
    const float* __restrict__ lw3, const float* __restrict__ lb3,
    const float* __restrict__ dw0, const float* __restrict__ db0,
    const float* __restrict__ dw1, const float* __restrict__ db1,
    const float* __restrict__ dw2, const float* __restrict__ db2,
    const float* __restrict__ dw3, const float* __restrict__ db3,
    float* __restrict__ out) {
    __shared__ float sH[4][8][HSTR];   // per-wave activation buffers (16.5 KB)
    __shared__ float sLg[4][8][25];    // per-wave logit buffers (3.2 KB)
    __shared__ float sTm[NJ * 12];
    __shared__ float sCond[NCD];

    const int tid = threadIdx.x;
    const int lane = tid & 63;
    const int wid = __builtin_amdgcn_readfirstlane(tid >> 6);
    const int r = lane >> 3;   // row 0..7 (problem within wave)
    const int cg = lane & 7;   // col-group 0..7
    const int jb = cg * 16;
    const int pi0w = blockIdx.x * PPB + wid * 8;
    const int b = (blockIdx.x * PPB) / NBSTRIDE;  // 18432 % 32 == 0
    const int pi = pi0w + r;

    for (int t = tid; t < NJ * 12; t += NTHR) {
        int j = t / 12, rc = t % 12;
        sTm[t] = tfs[(size_t)(b * NJ + j) * 16 + rc];
    }
    if (tid < NCD) sCond[tid] = cond[b * NCD + tid];
    __syncthreads();  // the only block barrier

    float* Hw = &sH[wid][0][0];
    float* Hrow = Hw + r * HSTR;
    float* Hval = Hw + (r & 4) * HSTR;  // value-channel row of this group (init)
    float* Lw = &sLg[wid][0][0];
    float* Lrow = Lw + r * 25;
    const float* Lbase = Lw + (r & 4) * 25;  // group's 4 channel rows (init)

    // own-row target (Broyden)
    const int pp = pi / NIB;
    const float tx = xd[pp * 3 + 0], ty = xd[pp * 3 + 1], tz = xd[pp * 3 + 2];

    // per-lane state (adopted during init)
    float x0_ = 0, x1_ = 0, x2_ = 0, g0 = 0, g1 = 0, g2 = 0;
    float Ji0 = 0, Ji1 = 0, Ji2 = 0, Ji3 = 0, Ji4 = 0, Ji5 = 0, Ji6 = 0, Ji7 = 0, Ji8 = 0;
    float u0 = 0, u1 = 0, u2 = 0, bx0 = 0, bx1 = 0, bx2 = 0, berr = 0;

    // ================= INIT: 4 passes, 2 problems (8 jacfwd rows) each ========
#pragma unroll 1
    for (int p = 0; p < 4; ++p) {
        const int q = pi0w + ((r < 4) ? p : p + 4);  // this group's problem
        const int ch = r & 3;                        // 0=value, 1..3=tangent d=ch-1
        const bool isval = (ch == 0);
        // bone-inverse point + target for q (replicated in all group lanes)
        const int ppq = q / NIB;
        const float txq = xd[ppq * 3 + 0], tyq = xd[ppq * 3 + 1], tzq = xd[ppq * 3 + 2];
        float xq0, xq1, xq2;
        {
            const float* T = tfs + (size_t)(b * NJ + bone_of(q % NIB)) * 16;
            float r00 = T[0], r01 = T[1], r02 = T[2], t0 = T[3];
            float r10 = T[4], r11 = T[5], r12 = T[6], t1 = T[7];
            float r20 = T[8], r21 = T[9], r22 = T[10], t2 = T[11];
            float det = r00 * (r11 * r22 - r12 * r21) - r01 * (r10 * r22 - r12 * r20) +
                        r02 * (r10 * r21 - r11 * r20);
            float rd = 1.0f / det;
            float vx = txq - t0, vy = tyq - t1, vz = tzq - t2;
            xq0 = ((r11 * r22 - r12 * r21) * vx - (r01 * r22 - r02 * r21) * vy +
                   (r01 * r12 - r02 * r11) * vz) * rd;
            xq1 = (-(r10 * r22 - r12 * r20) * vx + (r00 * r22 - r02 * r20) * vy -
                   (r00 * r12 - r02 * r10) * vz) * rd;
            xq2 = ((r10 * r21 - r11 * r20) * vx - (r00 * r21 - r01 * r20) * vy +
                   (r00 * r11 - r01 * r10) * vz) * rd;
        }
        // layer 0 (jacfwd): value rows = [x, cond] @ W0 + b0; tangent rows = W0[d]
        {
            float acc[16];
            if (isval) {
                load16(lb0 + jb, acc);
                fma16q(xq0, lw0 + 0 * NHID + jb, acc);
                fma16q(xq1, lw0 + 1 * NHID + jb, acc);
                fma16q(xq2, lw0 + 2 * NHID + jb, acc);
#pragma unroll
                for (int k = 0; k < NCD; k++) fma16q(sCond[k], lw0 + (3 + k) * NHID + jb, acc);
#pragma unroll
                for (int jj = 0; jj < 16; jj++) Hrow[jb + jj] = acc[jj];  // publish z
            } else {
                load16(lw0 + (ch - 1) * NHID + jb, acc);
            }
#pragma unroll
            for (int jj = 0; jj < 16; jj++) {
                float zv = Hval[jb + jj];
                Hrow[jb + jj] = isval ? softplusf(acc[jj]) : sigmoidf(zv) * acc[jj];
            }
        }
        hid_jac(lw1, lb1, Hrow, Hval, jb, isval);
        hid_jac(lw2, lb2, Hrow, Hval, jb, isval);
        logit_lay(lw3, lb3, Hrow, Lrow, cg, isval);

        // ---- J assembly (replicated in all 32 group lanes) ----
        {
            float mx = -1e30f;
#pragma unroll
            for (int j = 0; j < NJ; j++) mx = fmaxf(mx, SBLEND * Lbase[j]);
            float S = 0.0f;
#pragma unroll
            for (int j = 0; j < NJ; j++) S += expf(SBLEND * Lbase[j] - mx);
            const float invS = 1.0f / S;
            float d0 = 0, d1 = 0, d2 = 0;
#pragma unroll
            for (int j = 0; j < NJ; j++) {
                float sj = expf(SBLEND * Lbase[j] - mx) * invS;
                d0 += sj * (SBLEND * Lbase[25 + j]);
                d1 += sj * (SBLEND * Lbase[50 + j]);
                d2 += sj * (SBLEND * Lbase[75 + j]);
            }
            float f0 = 0, f1 = 0, f2 = 0;
            float J00 = 0, J01 = 0, J02 = 0, J10 = 0, J11 = 0, J12 = 0, J20 = 0, J21 = 0,
                  J22 = 0;
#pragma unroll
            for (int j = 0; j < NJ; j++) {
                float sj = expf(SBLEND * Lbase[j] - mx) * invS;
                float uj0 = SBLEND * Lbase[25 + j], uj1 = SBLEND * Lbase[50 + j],
                      uj2 = SBLEND * Lbase[75 + j];
                float sd0 = sj * (uj0 - d0), sd1 = sj * (uj1 - d1), sd2 = sj * (uj2 - d2);
                const float* M = &sTm[j * 12];
                float y0 = M[0] * xq0 + M[1] * xq1 + M[2] * xq2 + M[3];
                float y1 = M[4] * xq0 + M[5] * xq1 + M[6] * xq2 + M[7];
                float y2 = M[8] * xq0 + M[9] * xq1 + M[10] * xq2 + M[11];
                f0 += sj * y0; f1 += sj * y1; f2 += sj * y2;
                J00 += sd0 * y0 + sj * M[0]; J01 += sd1 * y0 + sj * M[1]; J02 += sd2 * y0 + sj * M[2];
                J10 += sd0 * y1 + sj * M[4]; J11 += sd1 * y1 + sj * M[5]; J12 += sd2 * y1 + sj * M[6];
                J20 += sd0 * y2 + sj * M[8]; J21 += sd1 * y2 + sj * M[9]; J22 += sd2 * y2 + sj * M[10];
            }
            float gq0 = f0 - txq, gq1 = f1 - tyq, gq2 = f2 - tzq;
            float detJ = J00 * (J11 * J22 - J12 * J21) - J01 * (J10 * J22 - J12 * J20) +
                         J02 * (J10 * J21 - J11 * J20);
            float rdJ = 1.0f / detJ;
            float K0 = (J11 * J22 - J12 * J21) * rdJ, K1 = -(J01 * J22 - J02 * J21) * rdJ,
                  K2 = (J01 * J12 - J02 * J11) * rdJ;
            float K3 = -(J10 * J22 - J12 * J20) * rdJ, K4 = (J00 * J22 - J02 * J20) * rdJ,
                  K5 = -(J00 * J12 - J02 * J10) * rdJ;
            float K6 = (J10 * J21 - J11 * J20) * rdJ, K7 = -(J00 * J21 - J01 * J20) * rdJ,
                  K8 = (J00 * J11 - J01 * J10) * rdJ;
            if ((r & 3) == p) {  // this lane's row == the problem just initialized
                x0_ = xq0; x1_ = xq1; x2_ = xq2;
                g0 = gq0; g1 = gq1; g2 = gq2;
                Ji0 = K0; Ji1 = K1; Ji2 = K2; Ji3 = K3; Ji4 = K4; Ji5 = K5;
                Ji6 = K6; Ji7 = K7; Ji8 = K8;
                u0 = -(K0 * gq0 + K1 * gq1 + K2 * gq2);
                u1 = -(K3 * gq0 + K4 * gq1 + K5 * gq2);
                u2 = -(K6 * gq0 + K7 * gq1 + K8 * gq2);
                berr = sqrtf(gq0 * gq0 + gq1 * gq1 + gq2 * gq2);
                bx0 = xq0; bx1 = xq1; bx2 = xq2;
            }
        }
    }

    // ================= BROYDEN: up to 50 iters, per-wave early exit ==========
#pragma unroll 1
    for (int it = 0; it < MAX_STEPS; ++it) {
        float dx0 = u0, dx1 = u1, dx2 = u2;
        x0_ += dx0; x1_ += dx1; x2_ += dx2;
        // layer 0 (value)
        {
            float acc[16];
            load16(lb0 + jb, acc);
            fma16q(x0_, lw0 + 0 * NHID + jb, acc);
            fma16q(x1_, lw0 + 1 * NHID + jb, acc);
            fma16q(x2_, lw0 + 2 * NHID + jb, acc);
#pragma unroll
            for (int k = 0; k < NCD; k++) fma16q(sCond[k], lw0 + (3 + k) * NHID + jb, acc);
#pragma unroll
            for (int jj = 0; jj < 16; jj++) Hrow[jb + jj] = softplusf(acc[jj]);
        }
        hid_val(lw1, lb1, Hrow, jb);
        hid_val(lw2, lb2, Hrow, jb);
        logit_lay(lw3, lb3, Hrow, Lrow, cg, true);

        broyden_step(Lrow, sTm, tx, ty, tz, dx0, dx1, dx2,
                     x0_, x1_, x2_, g0, g1, g2,
                     Ji0, Ji1, Ji2, Ji3, Ji4, Ji5, Ji6, Ji7, Ji8,
                     u0, u1, u2, bx0, bx1, bx2, berr);
        if (__all(berr < CVG_EPS)) break;  // all 8 rows of this wave converged
    }

    // ================= DISP MLP + output =====================================
    {
        float acc[16];
        load16(db0 + jb, acc);
        fma16q(bx0, dw0 + 0 * NHID + jb, acc);
        fma16q(bx1, dw0 + 1 * NHID + jb, acc);
        fma16q(bx2, dw0 + 2 * NHID + jb, acc);
#pragma unroll
        for (int k = 0; k < NCD; k++) fma16q(sCond[k], dw0 + (3 + k) * NHID + jb, acc);
#pragma unroll
        for (int jj = 0; jj < 16; jj++) Hrow[jb + jj] = softplusf(acc[jj]);
    }
    hid_val(dw1, db1, Hrow, jb);
    hid_val(dw2, db2, Hrow, jb);

    // final 128->3: per-lane partials over own 16 k, butterfly-reduce over cg
    float a0 = 0, a1 = 0, a2 = 0;
#pragma unroll
    for (int m = 0; m < 16; m++) {
        float h = Hrow[jb + m];
        const float* w = dw3 + (jb + m) * 3;
        a0 = fmaf(h, w[0], a0); a1 = fmaf(h, w[1], a1); a2 = fmaf(h, w[2], a2);
    }
    a0 += swzf<0x041F>(a0); a0 += swzf<0x081F>(a0); a0 += swzf<0x101F>(a0);
    a1 += swzf<0x041F>(a1); a1 += swzf<0x081F>(a1); a1 += swzf<0x101F>(a1);
    a2 += swzf<0x041F>(a2); a2 += swzf<0x081F>(a2); a2 += swzf<0x101F>(a2);
    if (cg == 0) {
        out[pi * 3 + 0] = bx0 + a0 + db3[0];
        out[pi * 3 + 1] = bx1 + a1 + db3[1];
        out[pi * 3 + 2] = bx2 + a2 + db3[2];
        out[3 * NPI + pi] = (berr < CVG_EPS) ? 1.0f : 0.0f;
    }
}

extern "C" void kernel_launch(void* const* d_in, const int* in_sizes, int n_in,
                              void* d_out, int out_size, void* d_ws, size_t ws_size,
                              hipStream_t stream) {
    (void)in_sizes; (void)n_in; (void)out_size; (void)d_ws; (void)ws_size;
    const float* xd   = (const float*)d_in[0];
    const float* cond = (const float*)d_in[1];
    const float* tfs  = (const float*)d_in[2];
    const float* lw0 = (const float*)d_in[3];  const float* lb0 = (const float*)d_in[4];
    const float* lw1 = (const float*)d_in[5];  const float* lb1 = (const float*)d_in[6];
    const float* lw2 = (const float*)d_in[7];  const float* lb2 = (const float*)d_in[8];
    const float* lw3 = (const float*)d_in[9];  const float* lb3 = (const float*)d_in[10];
    const float* dw0 = (const float*)d_in[11]; const float* db0 = (const float*)d_in[12];
    const float* dw1 = (const float*)d_in[13]; const float* db1 = (const float*)d_in[14];
    const float* dw2 = (const float*)d_in[15]; const float* db2 = (const float*)d_in[16];
    const float* dw3 = (const float*)d_in[17]; const float* db3 = (const float*)d_in[18];
    float* out = (float*)d_out;

    kernel_fused<<<NBLK, NTHR, 0, stream>>>(xd, cond, tfs, lw0, lb0, lw1, lb1, lw2, lb2,
                                            lw3, lb3, dw0, db0, dw1, db1, dw2, db2, dw3,
                                            db3, out);
}